// Round 13
// baseline (110.021 us; speedup 1.0000x reference)
//
#include <hip/hip_runtime.h>
#include <hip/hip_bf16.h>

#define S49 49
#define D128 128
#define NH 4
#define VTS 58   // vt row stride (ushorts): 116B = 29 banks mod 32 -> <=2-way b128 reads

typedef __attribute__((ext_vector_type(8))) short short8;
typedef __attribute__((ext_vector_type(4))) unsigned uint4v;
typedef __attribute__((ext_vector_type(4))) float f32x4;

__device__ __forceinline__ unsigned short f2b(float x){
  unsigned u = __builtin_bit_cast(unsigned, x);
  return (unsigned short)((u + 0x7fffu + ((u>>16)&1u)) >> 16);   // RNE
}
__device__ __forceinline__ unsigned pk2(float a, float b){
  __hip_bfloat162 h = __float22bfloat162_rn(float2{a, b});      // HW v_cvt_pk_bf16_f32
  unsigned u; __builtin_memcpy(&u, &h, 4);
  return u;
}
// XOR-swizzled LDS indexing (ushort units), 16B granule: conflict-free
// fragment reads at power-of-2 strides, no padding.
__device__ __forceinline__ int swz256i(int row, int col){  // 128-elem (256B) rows
  return row*128 + ((((col>>3) ^ (row&15)) << 3) | (col&7));
}
// permuted K-row for QK tile nt so that D-row (4lg+r) = kv 8lg+4(nt&1)+r+32(nt>>1):
// PV A-fragment (kv = 8lg..8lg+7 per lane) becomes LANE-LOCAL -> no P round-trip.
__device__ __forceinline__ int krow(int nt, int ln){
  return 8*(ln>>2) + (ln&3) + 4*(nt&1) + 32*(nt>>1);
}

// ---- K0: transpose weights to Wt[mat][n][k] bf16 in workspace ----
__global__ void prep_wt(const float* __restrict__ Wq, const float* __restrict__ Wk,
                        const float* __restrict__ Wv, unsigned short* __restrict__ wt){
  int e = blockIdx.x*256 + threadIdx.x;
  if (e >= 3*128*128) return;
  int mat = e >> 14, rem = e & 16383, n = rem >> 7, k = rem & 127;
  const float* W = (mat==0) ? Wq : ((mat==1) ? Wk : Wv);
  wt[e] = f2b(W[k*128 + n]);
}

// ---- K1: combined (mask + rel-pos-bias) table, PRE-SCALED by log2(e) ----
// slot s = nt*4+lg; comb4[(((w*NH+h)*49)+i)*16 + s].r = c(i, j(nt,lg,r))*log2e
// j = 8*lg + 4*(nt&1) + 32*(nt>>1) + r   (matches permuted-K D layout)
// pad j>=49 -> -1e30 so exp2 -> 0 exactly (also kills garbage-K rows).
__global__ void prep_comb(const float* __restrict__ mask, const float* __restrict__ bt,
                          float4* __restrict__ comb4, int nW){
  int e = blockIdx.x*256 + threadIdx.x;
  if (e >= nW*NH*S49*16) return;
  int s = e & 15; int nt = s >> 2, lg = s & 3;
  int t = e >> 4;
  int i = t % S49; t /= S49;
  int h = t & (NH-1); int w = t / NH;
  const float* mrow = mask + ((size_t)w*S49 + i)*S49;
  int ri = i/7, ci = i - ri*7;
  const float L2E = 1.4426950408889634f;
  float v[4];
  #pragma unroll
  for (int r = 0; r < 4; ++r){
    int j = 8*lg + 4*(nt&1) + 32*(nt>>1) + r;
    if (j < S49){
      int rj = j/7, cj = j - rj*7;
      int idx = (ri - rj + 6)*13 + (ci - cj + 6);
      v[r] = (mrow[j] + bt[idx*NH + h]) * L2E;
    } else v[r] = -1e30f;
  }
  float4 o; o.x = v[0]; o.y = v[1]; o.z = v[2]; o.w = v[3];
  comb4[e] = o;
}

// ---- main fused kernel: one block (8 waves) per window, 2 barriers, 3 blocks/CU ----
// wave = (row-tile rt = wave&3, head-pair hp = wave>>2). Swapped QK^T with
// permuted K rows -> P fully in registers; no P LDS, no shuffles.
__global__ __launch_bounds__(512, 6) void swin_attn(
    const float* __restrict__ hs,
    const float* __restrict__ bq, const float* __restrict__ bk,
    const float* __restrict__ bv,
    const float4* __restrict__ comb4,
    const unsigned short* __restrict__ wt, float* __restrict__ out, int nW){

  // 52480 B: hs 12544 | q 12544 | k 12544 | vt 14848  -> 3 blocks/CU (157440<=163840)
  __shared__ __align__(16) unsigned short lds[26240];
  unsigned short* hs_s = lds;              // 49x128 swz256i (dead after projection)
  unsigned short* q_s  = lds + 6272;       // 49x128 swz256i
  unsigned short* k_s  = lds + 12544;      // 49x128 swz256i (rows 49..63 read finite vt garbage; e=0 via comb)
  unsigned short* vt_s = lds + 18816;      // 128 x VTS linear (cols 48..57 zeroed)

  const int b = blockIdx.x;
  const int tid = threadIdx.x;
  const int wave = tid >> 6, lane = tid & 63;
  const int lg = lane >> 4, ln = lane & 15;

  // ---- stage hidden_states f32 -> bf16 LDS ----
  const float* hsb = hs + (size_t)b * (S49*D128);
  #pragma unroll
  for (int it = 0; it < 4; ++it) {
    int u = tid + it*512;                  // 1568 units of 4 f32
    if (u < S49*32) {
      int row = u >> 5, c = u & 31;
      float4 f = *(const float4*)(hsb + row*128 + c*4);
      uint2 o; o.x = pk2(f.x, f.y); o.y = pk2(f.z, f.w);
      *(uint2*)&hs_s[swz256i(row, c*4)] = o;
    }
  }
  // zero vt cols 48..57 (col 48 rewritten by projection); 640 aligned u32 writes
  #pragma unroll
  for (int it = 0; it < 2; ++it) {
    int u = tid + it*512;
    if (u < 128*5) {
      int row = u/5, cc = 48 + 2*(u - row*5);
      *(unsigned*)&vt_s[row*VTS + cc] = 0u;
    }
  }
  __syncthreads();

  const int w = b % nW;
  const int rt = wave & 3, hp = wave >> 2;
  const int mbw = (rt<3) ? rt*16 : 33;     // wave's q-row tile (overlap rows recompute identically)

  // ---- QKV projection: wave owns 16 output cols; Q,K,V processed sequentially ----
  {
    const int ntb = wave*16;
    #pragma unroll 1
    for (int mat = 0; mat < 3; ++mat) {
      short8 a[4];
      #pragma unroll
      for (int ks = 0; ks < 4; ++ks)
        a[ks] = *(const short8*)&wt[(mat<<14) + (ntb+ln)*128 + ks*32 + lg*8];
      const float* bp = (mat==0) ? bq : ((mat==1) ? bk : bv);
      float4 bias = *(const float4*)&bp[ntb + 4*lg];
      #pragma unroll
      for (int mt = 0; mt < 4; ++mt) {
        const int mb = (mt<3) ? mt*16 : 33;      // overlapping tiles cover rows 0..48
        short8 bh[4];
        #pragma unroll
        for (int ks = 0; ks < 4; ++ks)
          bh[ks] = *(const short8*)&hs_s[swz256i(mb+ln, ks*32 + lg*8)];
        f32x4 acc = {0.f,0.f,0.f,0.f};
        #pragma unroll
        for (int ks = 0; ks < 4; ++ks)
          acc = __builtin_amdgcn_mfma_f32_16x16x32_bf16(a[ks], bh[ks], acc, 0,0,0);
        // D transposed: col(ln) = token row m, rows(4lg+r) = output col n
        const int m = mb + ln;
        const int nb = ntb + 4*lg;
        if (mat == 0) {
          uint2 o; o.x = pk2(acc[0]+bias.x, acc[1]+bias.y);
                   o.y = pk2(acc[2]+bias.z, acc[3]+bias.w);
          *(uint2*)&q_s[swz256i(m, nb)] = o;
        } else if (mat == 1) {
          uint2 o; o.x = pk2(acc[0]+bias.x, acc[1]+bias.y);
                   o.y = pk2(acc[2]+bias.z, acc[3]+bias.w);
          *(uint2*)&k_s[swz256i(m, nb)] = o;
        } else {
          vt_s[(nb+0)*VTS + m] = f2b(acc[0]+bias.x);
          vt_s[(nb+1)*VTS + m] = f2b(acc[1]+bias.y);
          vt_s[(nb+2)*VTS + m] = f2b(acc[2]+bias.z);
          vt_s[(nb+3)*VTS + m] = f2b(acc[3]+bias.w);
        }
      }
    }
  }
  __syncthreads();
  // ---- attention: NO barriers (q/k/vt read-only; P stays in registers) ----

  const float C1 = 0.17677669529663687f * 1.4426950408889634f;  // scale * log2e
  const short8 z8 = {0,0,0,0,0,0,0,0};

  #pragma unroll
  for (int hh = 0; hh < 2; ++hh) {
    const int h = hp*2 + hh;
    float4 cb[4];
    #pragma unroll
    for (int nt = 0; nt < 4; ++nt)
      cb[nt] = comb4[((size_t)((w*NH + h)*S49) + mbw + ln)*16 + nt*4 + lg];

    // ---- S^T via mfma(K,Q) with permuted K rows ----
    short8 aq = *(const short8*)&q_s[swz256i(mbw+ln, h*32 + lg*8)];
    short8 kb[4];
    #pragma unroll
    for (int nt = 0; nt < 4; ++nt)
      kb[nt] = *(const short8*)&k_s[swz256i(krow(nt, ln), h*32 + lg*8)];
    f32x4 st[4];
    __builtin_amdgcn_s_setprio(1);
    #pragma unroll
    for (int nt = 0; nt < 4; ++nt) {
      f32x4 z = {0.f,0.f,0.f,0.f};
      st[nt] = __builtin_amdgcn_mfma_f32_16x16x32_bf16(kb[nt], aq, z, 0,0,0);
    }
    __builtin_amdgcn_s_setprio(0);

    // ---- lane-local max-free softmax; garbage/pad kv -> e=0 exactly via comb ----
    // lane holds q=ln, kv = 8lg + 4(nt&1) + r + 32(nt>>1)
    float e[4][4], psum[4];
    #pragma unroll
    for (int nt = 0; nt < 4; ++nt) {
      float cbv[4] = {cb[nt].x, cb[nt].y, cb[nt].z, cb[nt].w};
      #pragma unroll
      for (int r = 0; r < 4; ++r)
        e[nt][r] = __builtin_amdgcn_exp2f(fmaf(st[nt][r], C1, cbv[r]));
      psum[nt] = (e[nt][0] + e[nt][1]) + (e[nt][2] + e[nt][3]);
    }
    float sum = (psum[0] + psum[1]) + (psum[2] + psum[3]);
    sum += __shfl_xor(sum, 16, 64);
    sum += __shfl_xor(sum, 32, 64);
    const float inv = __builtin_amdgcn_rcpf(sum);

    // ---- P A-fragments assembled IN REGISTERS (normalized) ----
    uint4v u0, u1;
    u0.x = pk2(e[0][0]*inv, e[0][1]*inv);
    u0.y = pk2(e[0][2]*inv, e[0][3]*inv);
    u0.z = pk2(e[1][0]*inv, e[1][1]*inv);
    u0.w = pk2(e[1][2]*inv, e[1][3]*inv);
    u1.x = pk2(e[2][0]*inv, e[2][1]*inv);
    u1.y = pk2(e[2][2]*inv, e[2][3]*inv);
    u1.z = pk2(e[3][0]*inv, e[3][1]*inv);
    u1.w = pk2(e[3][2]*inv, e[3][3]*inv);
    short8 ap0 = __builtin_bit_cast(short8, u0);   // kv 8lg..8lg+7
    short8 ap1 = __builtin_bit_cast(short8, u1);   // kv 32+8lg..+7 (pads already 0)

    // ---- PV: B = V^T rows, 2-way-free stride-58 reads ----
    #pragma unroll
    for (int nt = 0; nt < 2; ++nt) {
      const int vr = h*32 + nt*16 + ln;             // output col == vt row
      short8 bv0 = *(const short8*)&vt_s[vr*VTS + lg*8];
      short8 bv1 = z8;
      if (lg < 3) bv1 = *(const short8*)&vt_s[vr*VTS + 32 + lg*8];  // lg=3: ap1=0 anyway; avoid OOB row 127
      f32x4 acc = {0.f,0.f,0.f,0.f};
      __builtin_amdgcn_s_setprio(1);
      acc = __builtin_amdgcn_mfma_f32_16x16x32_bf16(ap0, bv0, acc, 0,0,0);
      acc = __builtin_amdgcn_mfma_f32_16x16x32_bf16(ap1, bv1, acc, 0,0,0);
      __builtin_amdgcn_s_setprio(0);
      const int mr = mbw + 4*lg;
      #pragma unroll
      for (int r = 0; r < 4; ++r)
        out[((size_t)b*S49 + mr + r)*D128 + vr] = acc[r];
    }
  }
}

extern "C" void kernel_launch(void* const* d_in, const int* in_sizes, int n_in,
                              void* d_out, int out_size, void* d_ws, size_t ws_size,
                              hipStream_t stream){
  const float* hs  = (const float*)d_in[0];
  const float* msk = (const float*)d_in[1];
  const float* Wq  = (const float*)d_in[2];
  const float* bq  = (const float*)d_in[3];
  const float* Wk  = (const float*)d_in[4];
  const float* bk  = (const float*)d_in[5];
  const float* Wv  = (const float*)d_in[6];
  const float* bv  = (const float*)d_in[7];
  const float* bt  = (const float*)d_in[8];
  unsigned short* wt = (unsigned short*)d_ws;
  float4* comb4 = (float4*)((char*)d_ws + 98304);
  float* out = (float*)d_out;
  const int B  = in_sizes[0] / (S49*D128);
  const int nW = in_sizes[1] / (S49*S49);
  prep_wt<<<dim3((3*128*128 + 255)/256), dim3(256), 0, stream>>>(Wq, Wk, Wv, wt);
  prep_comb<<<dim3((nW*NH*S49*16 + 255)/256), dim3(256), 0, stream>>>(msk, bt, comb4, nW);
  swin_attn<<<dim3(B), dim3(512), 0, stream>>>(hs, bq, bk, bv, comb4, wt, out, nW);
}

// Round 14
// 109.156 us; speedup vs baseline: 1.0079x; 1.0079x over previous
//
#include <hip/hip_runtime.h>
#include <hip/hip_bf16.h>

#define S49 49
#define D128 128
#define NH 4
#define VTS 58   // vt row stride (ushorts): 116B = 29 banks mod 32 -> ~2-way b128 reads

typedef __attribute__((ext_vector_type(8))) short short8;
typedef __attribute__((ext_vector_type(4))) unsigned uint4v;
typedef __attribute__((ext_vector_type(4))) float f32x4;

__device__ __forceinline__ unsigned short f2b(float x){
  unsigned u = __builtin_bit_cast(unsigned, x);
  return (unsigned short)((u + 0x7fffu + ((u>>16)&1u)) >> 16);   // RNE
}
__device__ __forceinline__ unsigned pk2(float a, float b){
  __hip_bfloat162 h = __float22bfloat162_rn(float2{a, b});      // HW v_cvt_pk_bf16_f32
  unsigned u; __builtin_memcpy(&u, &h, 4);
  return u;
}
// XOR-swizzled LDS indexing (ushort units), 16B granule: conflict-free
// fragment reads at power-of-2 strides, no padding.
__device__ __forceinline__ int swz256i(int row, int col){  // 128-elem (256B) rows
  return row*128 + ((((col>>3) ^ (row&15)) << 3) | (col&7));
}
// permuted K-row for QK tile nt so that D-row (4lg+r) = kv 8lg+4(nt&1)+r+32(nt>>1):
// PV A-fragment (kv = 8lg..8lg+7 per lane) becomes LANE-LOCAL -> no P round-trip.
__device__ __forceinline__ int krow(int nt, int ln){
  return 8*(ln>>2) + (ln&3) + 4*(nt&1) + 32*(nt>>1);
}

// ---- K0: transpose weights to Wt[mat][n][k] bf16 in workspace ----
__global__ void prep_wt(const float* __restrict__ Wq, const float* __restrict__ Wk,
                        const float* __restrict__ Wv, unsigned short* __restrict__ wt){
  int e = blockIdx.x*256 + threadIdx.x;
  if (e >= 3*128*128) return;
  int mat = e >> 14, rem = e & 16383, n = rem >> 7, k = rem & 127;
  const float* W = (mat==0) ? Wq : ((mat==1) ? Wk : Wv);
  wt[e] = f2b(W[k*128 + n]);
}

// ---- K1: combined (mask + rel-pos-bias) table, PRE-SCALED by log2(e) ----
// slot s = nt*4+lg; comb4[(((w*NH+h)*49)+i)*16 + s].r = c(i, j(nt,lg,r))*log2e
// j = 8*lg + 4*(nt&1) + 32*(nt>>1) + r   (matches permuted-K D layout)
// pad j>=49 -> -1e30 so exp2 -> 0 exactly (also kills garbage-K rows).
__global__ void prep_comb(const float* __restrict__ mask, const float* __restrict__ bt,
                          float4* __restrict__ comb4, int nW){
  int e = blockIdx.x*256 + threadIdx.x;
  if (e >= nW*NH*S49*16) return;
  int s = e & 15; int nt = s >> 2, lg = s & 3;
  int t = e >> 4;
  int i = t % S49; t /= S49;
  int h = t & (NH-1); int w = t / NH;
  const float* mrow = mask + ((size_t)w*S49 + i)*S49;
  int ri = i/7, ci = i - ri*7;
  const float L2E = 1.4426950408889634f;
  float v[4];
  #pragma unroll
  for (int r = 0; r < 4; ++r){
    int j = 8*lg + 4*(nt&1) + 32*(nt>>1) + r;
    if (j < S49){
      int rj = j/7, cj = j - rj*7;
      int idx = (ri - rj + 6)*13 + (ci - cj + 6);
      v[r] = (mrow[j] + bt[idx*NH + h]) * L2E;
    } else v[r] = -1e30f;
  }
  float4 o; o.x = v[0]; o.y = v[1]; o.z = v[2]; o.w = v[3];
  comb4[e] = o;
}

// ---- main fused kernel: one block (8 waves) per window, 2 barriers, 3 blocks/CU ----
// wave = (row-tile rt = wave&3, head-pair hp = wave>>2). Swapped QK^T with
// permuted K rows -> P fully in registers. Normalization OFF the critical
// path: rowsum via mfma(P, ones) lands in exactly the (lg,r) slot the PV
// output needs; inv applied at store (round 9's overlap structure).
__global__ __launch_bounds__(512, 6) void swin_attn(
    const float* __restrict__ hs,
    const float* __restrict__ bq, const float* __restrict__ bk,
    const float* __restrict__ bv,
    const float4* __restrict__ comb4,
    const unsigned short* __restrict__ wt, float* __restrict__ out, int nW){

  // 52480 B: hs 12544 | q 12544 | k 12544 | vt 14848  -> 3 blocks/CU (157440<=163840)
  __shared__ __align__(16) unsigned short lds[26240];
  unsigned short* hs_s = lds;              // 49x128 swz256i (dead after projection)
  unsigned short* q_s  = lds + 6272;       // 49x128 swz256i
  unsigned short* k_s  = lds + 12544;      // 49x128 swz256i (rows 49..63 read finite vt garbage; e=0 via comb)
  unsigned short* vt_s = lds + 18816;      // 128 x VTS linear (cols 48..57 zeroed)

  const int b = blockIdx.x;
  const int tid = threadIdx.x;
  const int wave = tid >> 6, lane = tid & 63;
  const int lg = lane >> 4, ln = lane & 15;

  // ---- stage hidden_states f32 -> bf16 LDS ----
  const float* hsb = hs + (size_t)b * (S49*D128);
  #pragma unroll
  for (int it = 0; it < 4; ++it) {
    int u = tid + it*512;                  // 1568 units of 4 f32
    if (u < S49*32) {
      int row = u >> 5, c = u & 31;
      float4 f = *(const float4*)(hsb + row*128 + c*4);
      uint2 o; o.x = pk2(f.x, f.y); o.y = pk2(f.z, f.w);
      *(uint2*)&hs_s[swz256i(row, c*4)] = o;
    }
  }
  // zero vt cols 48..57 (col 48 rewritten by projection); 640 aligned u32 writes
  #pragma unroll
  for (int it = 0; it < 2; ++it) {
    int u = tid + it*512;
    if (u < 128*5) {
      int row = u/5, cc = 48 + 2*(u - row*5);
      *(unsigned*)&vt_s[row*VTS + cc] = 0u;
    }
  }
  __syncthreads();

  const int w = b % nW;
  const int rt = wave & 3, hp = wave >> 2;
  const int mbw = (rt<3) ? rt*16 : 33;     // wave's q-row tile (overlap rows recompute identically)

  // ---- QKV projection: wave owns 16 output cols; Q,K,V processed sequentially ----
  {
    const int ntb = wave*16;
    #pragma unroll 1
    for (int mat = 0; mat < 3; ++mat) {
      short8 a[4];
      #pragma unroll
      for (int ks = 0; ks < 4; ++ks)
        a[ks] = *(const short8*)&wt[(mat<<14) + (ntb+ln)*128 + ks*32 + lg*8];
      const float* bp = (mat==0) ? bq : ((mat==1) ? bk : bv);
      float4 bias = *(const float4*)&bp[ntb + 4*lg];
      #pragma unroll
      for (int mt = 0; mt < 4; ++mt) {
        const int mb = (mt<3) ? mt*16 : 33;      // overlapping tiles cover rows 0..48
        short8 bh[4];
        #pragma unroll
        for (int ks = 0; ks < 4; ++ks)
          bh[ks] = *(const short8*)&hs_s[swz256i(mb+ln, ks*32 + lg*8)];
        f32x4 acc = {0.f,0.f,0.f,0.f};
        #pragma unroll
        for (int ks = 0; ks < 4; ++ks)
          acc = __builtin_amdgcn_mfma_f32_16x16x32_bf16(a[ks], bh[ks], acc, 0,0,0);
        // D transposed: col(ln) = token row m, rows(4lg+r) = output col n
        const int m = mb + ln;
        const int nb = ntb + 4*lg;
        if (mat == 0) {
          uint2 o; o.x = pk2(acc[0]+bias.x, acc[1]+bias.y);
                   o.y = pk2(acc[2]+bias.z, acc[3]+bias.w);
          *(uint2*)&q_s[swz256i(m, nb)] = o;
        } else if (mat == 1) {
          uint2 o; o.x = pk2(acc[0]+bias.x, acc[1]+bias.y);
                   o.y = pk2(acc[2]+bias.z, acc[3]+bias.w);
          *(uint2*)&k_s[swz256i(m, nb)] = o;
        } else {
          vt_s[(nb+0)*VTS + m] = f2b(acc[0]+bias.x);
          vt_s[(nb+1)*VTS + m] = f2b(acc[1]+bias.y);
          vt_s[(nb+2)*VTS + m] = f2b(acc[2]+bias.z);
          vt_s[(nb+3)*VTS + m] = f2b(acc[3]+bias.w);
        }
      }
    }
  }
  __syncthreads();
  // ---- attention: NO barriers (q/k/vt read-only; P stays in registers) ----

  const float C1 = 0.17677669529663687f * 1.4426950408889634f;  // scale * log2e
  const short8 ones = {16256,16256,16256,16256,16256,16256,16256,16256};  // bf16 1.0
  const short8 z8 = {0,0,0,0,0,0,0,0};

  #pragma unroll
  for (int hh = 0; hh < 2; ++hh) {
    const int h = hp*2 + hh;
    float4 cb[4];
    #pragma unroll
    for (int nt = 0; nt < 4; ++nt)
      cb[nt] = comb4[((size_t)((w*NH + h)*S49) + mbw + ln)*16 + nt*4 + lg];

    // ---- S^T via mfma(K,Q) with permuted K rows ----
    short8 aq = *(const short8*)&q_s[swz256i(mbw+ln, h*32 + lg*8)];
    short8 kb[4];
    #pragma unroll
    for (int nt = 0; nt < 4; ++nt)
      kb[nt] = *(const short8*)&k_s[swz256i(krow(nt, ln), h*32 + lg*8)];
    f32x4 st[4];
    __builtin_amdgcn_s_setprio(1);
    #pragma unroll
    for (int nt = 0; nt < 4; ++nt) {
      f32x4 z = {0.f,0.f,0.f,0.f};
      st[nt] = __builtin_amdgcn_mfma_f32_16x16x32_bf16(kb[nt], aq, z, 0,0,0);
    }
    __builtin_amdgcn_s_setprio(0);

    // ---- lane-local max-free exp (UNNORMALIZED); garbage/pad kv -> 0 via comb ----
    // lane holds q=ln, kv = 8lg + 4(nt&1) + r + 32(nt>>1)
    float e[4][4];
    #pragma unroll
    for (int nt = 0; nt < 4; ++nt) {
      float cbv[4] = {cb[nt].x, cb[nt].y, cb[nt].z, cb[nt].w};
      #pragma unroll
      for (int r = 0; r < 4; ++r)
        e[nt][r] = __builtin_amdgcn_exp2f(fmaf(st[nt][r], C1, cbv[r]));
    }

    // ---- P A-fragments assembled IN REGISTERS (unnormalized) ----
    uint4v u0, u1;
    u0.x = pk2(e[0][0], e[0][1]);
    u0.y = pk2(e[0][2], e[0][3]);
    u0.z = pk2(e[1][0], e[1][1]);
    u0.w = pk2(e[1][2], e[1][3]);
    u1.x = pk2(e[2][0], e[2][1]);
    u1.y = pk2(e[2][2], e[2][3]);
    u1.z = pk2(e[3][0], e[3][1]);
    u1.w = pk2(e[3][2], e[3][3]);
    short8 ap0 = __builtin_bit_cast(short8, u0);   // kv 8lg..8lg+7
    short8 ap1 = __builtin_bit_cast(short8, u1);   // kv 32+8lg..+7 (pads are 0)

    // ---- rowsum via mfma(P, ones): sacc[r] = sum_kv P[q=4lg+r][kv] ----
    // runs on the MFMA pipe concurrently with PV; inv needed only at store
    f32x4 sacc = {0.f,0.f,0.f,0.f};
    __builtin_amdgcn_s_setprio(1);
    sacc = __builtin_amdgcn_mfma_f32_16x16x32_bf16(ap0, ones, sacc, 0,0,0);
    sacc = __builtin_amdgcn_mfma_f32_16x16x32_bf16(ap1, ones, sacc, 0,0,0);
    __builtin_amdgcn_s_setprio(0);

    // ---- PV: B = V^T rows; normalize at store ----
    #pragma unroll
    for (int nt = 0; nt < 2; ++nt) {
      const int vr = h*32 + nt*16 + ln;             // output col == vt row
      short8 bv0 = *(const short8*)&vt_s[vr*VTS + lg*8];
      short8 bv1 = z8;
      if (lg < 3) bv1 = *(const short8*)&vt_s[vr*VTS + 32 + lg*8];  // lg=3: ap1 covers kv 56..63 = pads (0)
      f32x4 acc = {0.f,0.f,0.f,0.f};
      __builtin_amdgcn_s_setprio(1);
      acc = __builtin_amdgcn_mfma_f32_16x16x32_bf16(ap0, bv0, acc, 0,0,0);
      acc = __builtin_amdgcn_mfma_f32_16x16x32_bf16(ap1, bv1, acc, 0,0,0);
      __builtin_amdgcn_s_setprio(0);
      const int mr = mbw + 4*lg;
      #pragma unroll
      for (int r = 0; r < 4; ++r)
        out[((size_t)b*S49 + mr + r)*D128 + vr] = acc[r]*__builtin_amdgcn_rcpf(sacc[r]);
    }
  }
}

extern "C" void kernel_launch(void* const* d_in, const int* in_sizes, int n_in,
                              void* d_out, int out_size, void* d_ws, size_t ws_size,
                              hipStream_t stream){
  const float* hs  = (const float*)d_in[0];
  const float* msk = (const float*)d_in[1];
  const float* Wq  = (const float*)d_in[2];
  const float* bq  = (const float*)d_in[3];
  const float* Wk  = (const float*)d_in[4];
  const float* bk  = (const float*)d_in[5];
  const float* Wv  = (const float*)d_in[6];
  const float* bv  = (const float*)d_in[7];
  const float* bt  = (const float*)d_in[8];
  unsigned short* wt = (unsigned short*)d_ws;
  float4* comb4 = (float4*)((char*)d_ws + 98304);
  float* out = (float*)d_out;
  const int B  = in_sizes[0] / (S49*D128);
  const int nW = in_sizes[1] / (S49*S49);
  prep_wt<<<dim3((3*128*128 + 255)/256), dim3(256), 0, stream>>>(Wq, Wk, Wv, wt);
  prep_comb<<<dim3((nW*NH*S49*16 + 255)/256), dim3(256), 0, stream>>>(msk, bt, comb4, nW);
  swin_attn<<<dim3(B), dim3(512), 0, stream>>>(hs, bq, bk, bv, comb4, wt, out, nW);
}

// Round 15
// 101.560 us; speedup vs baseline: 1.0833x; 1.0748x over previous
//
#include <hip/hip_runtime.h>
#include <hip/hip_bf16.h>

#define S49 49
#define D128 128
#define NH 4
#define VTS 58   // vt row stride (ushorts): 116B = 29 banks mod 32 -> ~2-way b128 reads

typedef __attribute__((ext_vector_type(8))) short short8;
typedef __attribute__((ext_vector_type(4))) unsigned uint4v;
typedef __attribute__((ext_vector_type(4))) float f32x4;

__device__ __forceinline__ unsigned short f2b(float x){
  unsigned u = __builtin_bit_cast(unsigned, x);
  return (unsigned short)((u + 0x7fffu + ((u>>16)&1u)) >> 16);   // RNE
}
__device__ __forceinline__ unsigned pk2(float a, float b){
  __hip_bfloat162 h = __float22bfloat162_rn(float2{a, b});      // HW v_cvt_pk_bf16_f32
  unsigned u; __builtin_memcpy(&u, &h, 4);
  return u;
}
// XOR-swizzled LDS indexing (ushort units), 16B granule: conflict-free
// fragment reads at power-of-2 strides, no padding.
__device__ __forceinline__ int swz256i(int row, int col){  // 128-elem (256B) rows
  return row*128 + ((((col>>3) ^ (row&15)) << 3) | (col&7));
}
// permuted K-row for QK tile nt so that D-row (4lg+r) = kv 8lg+4(nt&1)+r+32(nt>>1):
// PV A-fragment (kv = 8lg..8lg+7 per lane) becomes LANE-LOCAL -> no P round-trip.
__device__ __forceinline__ int krow(int nt, int ln){
  return 8*(ln>>2) + (ln&3) + 4*(nt&1) + 32*(nt>>1);
}

// ---- K0: transpose weights to Wt[mat][n][k] bf16 in workspace ----
__global__ void prep_wt(const float* __restrict__ Wq, const float* __restrict__ Wk,
                        const float* __restrict__ Wv, unsigned short* __restrict__ wt){
  int e = blockIdx.x*256 + threadIdx.x;
  if (e >= 3*128*128) return;
  int mat = e >> 14, rem = e & 16383, n = rem >> 7, k = rem & 127;
  const float* W = (mat==0) ? Wq : ((mat==1) ? Wk : Wv);
  wt[e] = f2b(W[k*128 + n]);
}

// ---- K1: combined (mask + rel-pos-bias) table, PRE-SCALED by log2(e) ----
// LANE-COALESCED layout: comb4[(((w*NH+h)*4 + rt)*4 + nt)*64 + lane]
//   lane = lg*16+ln; q-row i = tile(rt)+ln, tile = {0,16,32,33}
//   .r = c(i, j)*log2e with j = 8*lg + 4*(nt&1) + 32*(nt>>1) + r  (permuted-K D layout)
// pad j>=49 -> -1e30 so exp2 -> 0 exactly (also kills garbage-K rows).
__global__ void prep_comb(const float* __restrict__ mask, const float* __restrict__ bt,
                          float4* __restrict__ comb4, int nW){
  int e = blockIdx.x*256 + threadIdx.x;
  if (e >= nW*NH*4*4*64) return;
  int lane = e & 63; int lg = lane >> 4, ln = lane & 15;
  int t = e >> 6;
  int nt = t & 3; t >>= 2;
  int rt = t & 3; t >>= 2;
  int h  = t & (NH-1); int w = t >> 2;
  const int tile = (rt<3) ? rt*16 : 33;
  const int i = tile + ln;
  const float* mrow = mask + ((size_t)w*S49 + i)*S49;
  int ri = i/7, ci = i - ri*7;
  const float L2E = 1.4426950408889634f;
  float v[4];
  #pragma unroll
  for (int r = 0; r < 4; ++r){
    int j = 8*lg + 4*(nt&1) + 32*(nt>>1) + r;
    if (j < S49){
      int rj = j/7, cj = j - rj*7;
      int idx = (ri - rj + 6)*13 + (ci - cj + 6);
      v[r] = (mrow[j] + bt[idx*NH + h]) * L2E;
    } else v[r] = -1e30f;
  }
  float4 o; o.x = v[0]; o.y = v[1]; o.z = v[2]; o.w = v[3];
  comb4[e] = o;
}

// ---- main fused kernel: one block (8 waves) per window, 2 barriers, 3 blocks/CU ----
// wave = (row-tile rt = wave&3, head-pair hp = wave>>2). Swapped QK^T with
// permuted K rows -> P fully in registers. Normalization off the critical
// path (rowsum via mfma(P,ones); inv at store). cb loads lane-coalesced.
__global__ __launch_bounds__(512, 6) void swin_attn(
    const float* __restrict__ hs,
    const float* __restrict__ bq, const float* __restrict__ bk,
    const float* __restrict__ bv,
    const float4* __restrict__ comb4,
    const unsigned short* __restrict__ wt, float* __restrict__ out, int nW){

  // 52480 B: hs 12544 | q 12544 | k 12544 | vt 14848  -> 3 blocks/CU (157440<=163840)
  __shared__ __align__(16) unsigned short lds[26240];
  unsigned short* hs_s = lds;              // 49x128 swz256i (dead after projection)
  unsigned short* q_s  = lds + 6272;       // 49x128 swz256i
  unsigned short* k_s  = lds + 12544;      // 49x128 swz256i (rows 49..63 read finite vt garbage; e=0 via comb)
  unsigned short* vt_s = lds + 18816;      // 128 x VTS linear (cols 48..57 zeroed)

  const int b = blockIdx.x;
  const int tid = threadIdx.x;
  const int wave = tid >> 6, lane = tid & 63;
  const int lg = lane >> 4, ln = lane & 15;

  // ---- stage hidden_states f32 -> bf16 LDS ----
  const float* hsb = hs + (size_t)b * (S49*D128);
  #pragma unroll
  for (int it = 0; it < 4; ++it) {
    int u = tid + it*512;                  // 1568 units of 4 f32
    if (u < S49*32) {
      int row = u >> 5, c = u & 31;
      float4 f = *(const float4*)(hsb + row*128 + c*4);
      uint2 o; o.x = pk2(f.x, f.y); o.y = pk2(f.z, f.w);
      *(uint2*)&hs_s[swz256i(row, c*4)] = o;
    }
  }
  // zero vt cols 48..57 (col 48 rewritten by projection); 640 aligned u32 writes
  #pragma unroll
  for (int it = 0; it < 2; ++it) {
    int u = tid + it*512;
    if (u < 128*5) {
      int row = u/5, cc = 48 + 2*(u - row*5);
      *(unsigned*)&vt_s[row*VTS + cc] = 0u;
    }
  }
  __syncthreads();

  const int w = b % nW;
  const int rt = wave & 3, hp = wave >> 2;
  const int mbw = (rt<3) ? rt*16 : 33;     // wave's q-row tile (overlap rows recompute identically)

  // ---- QKV projection: wave owns 16 output cols; Q,K,V processed sequentially ----
  {
    const int ntb = wave*16;
    #pragma unroll 1
    for (int mat = 0; mat < 3; ++mat) {
      short8 a[4];
      #pragma unroll
      for (int ks = 0; ks < 4; ++ks)
        a[ks] = *(const short8*)&wt[(mat<<14) + (ntb+ln)*128 + ks*32 + lg*8];
      const float* bp = (mat==0) ? bq : ((mat==1) ? bk : bv);
      float4 bias = *(const float4*)&bp[ntb + 4*lg];
      #pragma unroll
      for (int mt = 0; mt < 4; ++mt) {
        const int mb = (mt<3) ? mt*16 : 33;      // overlapping tiles cover rows 0..48
        short8 bh[4];
        #pragma unroll
        for (int ks = 0; ks < 4; ++ks)
          bh[ks] = *(const short8*)&hs_s[swz256i(mb+ln, ks*32 + lg*8)];
        f32x4 acc = {0.f,0.f,0.f,0.f};
        #pragma unroll
        for (int ks = 0; ks < 4; ++ks)
          acc = __builtin_amdgcn_mfma_f32_16x16x32_bf16(a[ks], bh[ks], acc, 0,0,0);
        // D transposed: col(ln) = token row m, rows(4lg+r) = output col n
        const int m = mb + ln;
        const int nb = ntb + 4*lg;
        if (mat == 0) {
          uint2 o; o.x = pk2(acc[0]+bias.x, acc[1]+bias.y);
                   o.y = pk2(acc[2]+bias.z, acc[3]+bias.w);
          *(uint2*)&q_s[swz256i(m, nb)] = o;
        } else if (mat == 1) {
          uint2 o; o.x = pk2(acc[0]+bias.x, acc[1]+bias.y);
                   o.y = pk2(acc[2]+bias.z, acc[3]+bias.w);
          *(uint2*)&k_s[swz256i(m, nb)] = o;
        } else {
          vt_s[(nb+0)*VTS + m] = f2b(acc[0]+bias.x);
          vt_s[(nb+1)*VTS + m] = f2b(acc[1]+bias.y);
          vt_s[(nb+2)*VTS + m] = f2b(acc[2]+bias.z);
          vt_s[(nb+3)*VTS + m] = f2b(acc[3]+bias.w);
        }
      }
    }
  }
  __syncthreads();
  // ---- attention: NO barriers (q/k/vt read-only; P stays in registers) ----

  const float C1 = 0.17677669529663687f * 1.4426950408889634f;  // scale * log2e
  const short8 ones = {16256,16256,16256,16256,16256,16256,16256,16256};  // bf16 1.0
  const short8 z8 = {0,0,0,0,0,0,0,0};
  const float4* cbase = comb4 + ((size_t)(w*NH)*4 + rt)*4*64 + lane;  // + h*1024 per head

  #pragma unroll
  for (int hh = 0; hh < 2; ++hh) {
    const int h = hp*2 + hh;
    // lane-coalesced combined bias+mask: 4 contiguous-1KB loads
    float4 cb[4];
    #pragma unroll
    for (int nt = 0; nt < 4; ++nt)
      cb[nt] = cbase[h*1024 + nt*64];

    // ---- S^T via mfma(K,Q) with permuted K rows ----
    short8 aq = *(const short8*)&q_s[swz256i(mbw+ln, h*32 + lg*8)];
    short8 kb[4];
    #pragma unroll
    for (int nt = 0; nt < 4; ++nt)
      kb[nt] = *(const short8*)&k_s[swz256i(krow(nt, ln), h*32 + lg*8)];
    f32x4 st[4];
    __builtin_amdgcn_s_setprio(1);
    #pragma unroll
    for (int nt = 0; nt < 4; ++nt) {
      f32x4 z = {0.f,0.f,0.f,0.f};
      st[nt] = __builtin_amdgcn_mfma_f32_16x16x32_bf16(kb[nt], aq, z, 0,0,0);
    }
    __builtin_amdgcn_s_setprio(0);

    // ---- lane-local max-free exp (UNNORMALIZED); garbage/pad kv -> 0 via comb ----
    // lane holds q=ln, kv = 8lg + 4(nt&1) + r + 32(nt>>1)
    float e[4][4];
    #pragma unroll
    for (int nt = 0; nt < 4; ++nt) {
      float cbv[4] = {cb[nt].x, cb[nt].y, cb[nt].z, cb[nt].w};
      #pragma unroll
      for (int r = 0; r < 4; ++r)
        e[nt][r] = __builtin_amdgcn_exp2f(fmaf(st[nt][r], C1, cbv[r]));
    }

    // ---- P A-fragments assembled IN REGISTERS (unnormalized) ----
    uint4v u0, u1;
    u0.x = pk2(e[0][0], e[0][1]);
    u0.y = pk2(e[0][2], e[0][3]);
    u0.z = pk2(e[1][0], e[1][1]);
    u0.w = pk2(e[1][2], e[1][3]);
    u1.x = pk2(e[2][0], e[2][1]);
    u1.y = pk2(e[2][2], e[2][3]);
    u1.z = pk2(e[3][0], e[3][1]);
    u1.w = pk2(e[3][2], e[3][3]);
    short8 ap0 = __builtin_bit_cast(short8, u0);   // kv 8lg..8lg+7
    short8 ap1 = __builtin_bit_cast(short8, u1);   // kv 32+8lg..+7 (pads are 0)

    // ---- rowsum via mfma(P, ones): sacc[r] = sum_kv P[q=4lg+r][kv] ----
    // runs on the MFMA pipe concurrently with PV; inv needed only at store
    f32x4 sacc = {0.f,0.f,0.f,0.f};
    __builtin_amdgcn_s_setprio(1);
    sacc = __builtin_amdgcn_mfma_f32_16x16x32_bf16(ap0, ones, sacc, 0,0,0);
    sacc = __builtin_amdgcn_mfma_f32_16x16x32_bf16(ap1, ones, sacc, 0,0,0);
    __builtin_amdgcn_s_setprio(0);

    // ---- PV: B = V^T rows; normalize at store ----
    #pragma unroll
    for (int nt = 0; nt < 2; ++nt) {
      const int vr = h*32 + nt*16 + ln;             // output col == vt row
      short8 bv0 = *(const short8*)&vt_s[vr*VTS + lg*8];
      short8 bv1 = z8;
      if (lg < 3) bv1 = *(const short8*)&vt_s[vr*VTS + 32 + lg*8];  // lg=3: ap1 covers kv 56..63 = pads (0)
      f32x4 acc = {0.f,0.f,0.f,0.f};
      __builtin_amdgcn_s_setprio(1);
      acc = __builtin_amdgcn_mfma_f32_16x16x32_bf16(ap0, bv0, acc, 0,0,0);
      acc = __builtin_amdgcn_mfma_f32_16x16x32_bf16(ap1, bv1, acc, 0,0,0);
      __builtin_amdgcn_s_setprio(0);
      const int mr = mbw + 4*lg;
      #pragma unroll
      for (int r = 0; r < 4; ++r)
        out[((size_t)b*S49 + mr + r)*D128 + vr] = acc[r]*__builtin_amdgcn_rcpf(sacc[r]);
    }
  }
}

extern "C" void kernel_launch(void* const* d_in, const int* in_sizes, int n_in,
                              void* d_out, int out_size, void* d_ws, size_t ws_size,
                              hipStream_t stream){
  const float* hs  = (const float*)d_in[0];
  const float* msk = (const float*)d_in[1];
  const float* Wq  = (const float*)d_in[2];
  const float* bq  = (const float*)d_in[3];
  const float* Wk  = (const float*)d_in[4];
  const float* bk  = (const float*)d_in[5];
  const float* Wv  = (const float*)d_in[6];
  const float* bv  = (const float*)d_in[7];
  const float* bt  = (const float*)d_in[8];
  unsigned short* wt = (unsigned short*)d_ws;
  float4* comb4 = (float4*)((char*)d_ws + 98304);
  float* out = (float*)d_out;
  const int B  = in_sizes[0] / (S49*D128);
  const int nW = in_sizes[1] / (S49*S49);
  prep_wt<<<dim3((3*128*128 + 255)/256), dim3(256), 0, stream>>>(Wq, Wk, Wv, wt);
  prep_comb<<<dim3((nW*NH*4*4*64 + 255)/256), dim3(256), 0, stream>>>(msk, bt, comb4, nW);
  swin_attn<<<dim3(B), dim3(512), 0, stream>>>(hs, bq, bk, bv, comb4, wt, out, nW);
}

// Round 16
// 100.908 us; speedup vs baseline: 1.0903x; 1.0065x over previous
//
#include <hip/hip_runtime.h>
#include <hip/hip_bf16.h>

#define S49 49
#define D128 128
#define NH 4
#define VTS 58   // vt row stride (ushorts): 116B = 29 banks mod 32 -> ~2-way b128 reads

typedef __attribute__((ext_vector_type(8))) short short8;
typedef __attribute__((ext_vector_type(4))) unsigned uint4v;
typedef __attribute__((ext_vector_type(4))) float f32x4;

__device__ __forceinline__ unsigned short f2b(float x){
  unsigned u = __builtin_bit_cast(unsigned, x);
  return (unsigned short)((u + 0x7fffu + ((u>>16)&1u)) >> 16);   // RNE
}
__device__ __forceinline__ unsigned pk2(float a, float b){
  __hip_bfloat162 h = __float22bfloat162_rn(float2{a, b});      // HW v_cvt_pk_bf16_f32
  unsigned u; __builtin_memcpy(&u, &h, 4);
  return u;
}
// XOR-swizzled LDS indexing (ushort units), 16B granule: conflict-free
// fragment reads at power-of-2 strides, no padding.
__device__ __forceinline__ int swz256i(int row, int col){  // 128-elem (256B) rows
  return row*128 + ((((col>>3) ^ (row&15)) << 3) | (col&7));
}
// permuted K-row for QK tile nt so that D-row (4lg+r) = kv 8lg+4(nt&1)+r+32(nt>>1):
// PV A-fragment (kv = 8lg..8lg+7 per lane) becomes LANE-LOCAL -> no P round-trip.
__device__ __forceinline__ int krow(int nt, int ln){
  return 8*(ln>>2) + (ln&3) + 4*(nt&1) + 32*(nt>>1);
}

// ---- K0: transpose weights to Wt[mat][n][k] bf16 in workspace ----
__global__ void prep_wt(const float* __restrict__ Wq, const float* __restrict__ Wk,
                        const float* __restrict__ Wv, unsigned short* __restrict__ wt){
  int e = blockIdx.x*256 + threadIdx.x;
  if (e >= 3*128*128) return;
  int mat = e >> 14, rem = e & 16383, n = rem >> 7, k = rem & 127;
  const float* W = (mat==0) ? Wq : ((mat==1) ? Wk : Wv);
  wt[e] = f2b(W[k*128 + n]);
}

// ---- K1: combined (mask + rel-pos-bias) table, PRE-SCALED by log2(e) ----
// LANE-COALESCED layout: comb4[(((w*NH+h)*4 + rt)*4 + nt)*64 + lane]
//   lane = lg*16+ln; q-row i = tile(rt)+ln, tile = {0,16,32,33}
//   .r = c(i, j)*log2e with j = 8*lg + 4*(nt&1) + 32*(nt>>1) + r  (permuted-K D layout)
// pad j>=49 -> -1e30 so exp2 -> 0 exactly (also kills garbage-K rows).
__global__ void prep_comb(const float* __restrict__ mask, const float* __restrict__ bt,
                          float4* __restrict__ comb4, int nW){
  int e = blockIdx.x*256 + threadIdx.x;
  if (e >= nW*NH*4*4*64) return;
  int lane = e & 63; int lg = lane >> 4, ln = lane & 15;
  int t = e >> 6;
  int nt = t & 3; t >>= 2;
  int rt = t & 3; t >>= 2;
  int h  = t & (NH-1); int w = t >> 2;
  const int tile = (rt<3) ? rt*16 : 33;
  const int i = tile + ln;
  const float* mrow = mask + ((size_t)w*S49 + i)*S49;
  int ri = i/7, ci = i - ri*7;
  const float L2E = 1.4426950408889634f;
  float v[4];
  #pragma unroll
  for (int r = 0; r < 4; ++r){
    int j = 8*lg + 4*(nt&1) + 32*(nt>>1) + r;
    if (j < S49){
      int rj = j/7, cj = j - rj*7;
      int idx = (ri - rj + 6)*13 + (ci - cj + 6);
      v[r] = (mrow[j] + bt[idx*NH + h]) * L2E;
    } else v[r] = -1e30f;
  }
  float4 o; o.x = v[0]; o.y = v[1]; o.z = v[2]; o.w = v[3];
  comb4[e] = o;
}

// ---- main fused kernel: one block (8 waves) per window, 2 barriers, 3 blocks/CU ----
// wave = (row-tile rt = wave&3, head-pair hp = wave>>2). Swapped QK^T with
// permuted K rows -> P fully in registers. Normalization off the critical
// path (rowsum via mfma(P,ones); inv at store). cb loads lane-coalesced.
// NO setprio (scheduler fences); both heads' Q/K frags hoisted for ILP.
__global__ __launch_bounds__(512, 6) void swin_attn(
    const float* __restrict__ hs,
    const float* __restrict__ bq, const float* __restrict__ bk,
    const float* __restrict__ bv,
    const float4* __restrict__ comb4,
    const unsigned short* __restrict__ wt, float* __restrict__ out, int nW){

  // 52480 B: hs 12544 | q 12544 | k 12544 | vt 14848  -> 3 blocks/CU (157440<=163840)
  __shared__ __align__(16) unsigned short lds[26240];
  unsigned short* hs_s = lds;              // 49x128 swz256i (dead after projection)
  unsigned short* q_s  = lds + 6272;       // 49x128 swz256i
  unsigned short* k_s  = lds + 12544;      // 49x128 swz256i (rows 49..63 read finite vt garbage; e=0 via comb)
  unsigned short* vt_s = lds + 18816;      // 128 x VTS linear (cols 48..57 zeroed)

  const int b = blockIdx.x;
  const int tid = threadIdx.x;
  const int wave = tid >> 6, lane = tid & 63;
  const int lg = lane >> 4, ln = lane & 15;

  // ---- stage hidden_states f32 -> bf16 LDS ----
  const float* hsb = hs + (size_t)b * (S49*D128);
  #pragma unroll
  for (int it = 0; it < 4; ++it) {
    int u = tid + it*512;                  // 1568 units of 4 f32
    if (u < S49*32) {
      int row = u >> 5, c = u & 31;
      float4 f = *(const float4*)(hsb + row*128 + c*4);
      uint2 o; o.x = pk2(f.x, f.y); o.y = pk2(f.z, f.w);
      *(uint2*)&hs_s[swz256i(row, c*4)] = o;
    }
  }
  // zero vt cols 48..57 (col 48 rewritten by projection); 640 aligned u32 writes
  #pragma unroll
  for (int it = 0; it < 2; ++it) {
    int u = tid + it*512;
    if (u < 128*5) {
      int row = u/5, cc = 48 + 2*(u - row*5);
      *(unsigned*)&vt_s[row*VTS + cc] = 0u;
    }
  }
  __syncthreads();

  const int w = b % nW;
  const int rt = wave & 3, hp = wave >> 2;
  const int mbw = (rt<3) ? rt*16 : 33;     // wave's q-row tile (overlap rows recompute identically)

  // ---- QKV projection: wave owns 16 output cols; Q,K,V processed sequentially ----
  {
    const int ntb = wave*16;
    #pragma unroll 1
    for (int mat = 0; mat < 3; ++mat) {
      short8 a[4];
      #pragma unroll
      for (int ks = 0; ks < 4; ++ks)
        a[ks] = *(const short8*)&wt[(mat<<14) + (ntb+ln)*128 + ks*32 + lg*8];
      const float* bp = (mat==0) ? bq : ((mat==1) ? bk : bv);
      float4 bias = *(const float4*)&bp[ntb + 4*lg];
      #pragma unroll
      for (int mt = 0; mt < 4; ++mt) {
        const int mb = (mt<3) ? mt*16 : 33;      // overlapping tiles cover rows 0..48
        short8 bh[4];
        #pragma unroll
        for (int ks = 0; ks < 4; ++ks)
          bh[ks] = *(const short8*)&hs_s[swz256i(mb+ln, ks*32 + lg*8)];
        f32x4 acc = {0.f,0.f,0.f,0.f};
        #pragma unroll
        for (int ks = 0; ks < 4; ++ks)
          acc = __builtin_amdgcn_mfma_f32_16x16x32_bf16(a[ks], bh[ks], acc, 0,0,0);
        // D transposed: col(ln) = token row m, rows(4lg+r) = output col n
        const int m = mb + ln;
        const int nb = ntb + 4*lg;
        if (mat == 0) {
          uint2 o; o.x = pk2(acc[0]+bias.x, acc[1]+bias.y);
                   o.y = pk2(acc[2]+bias.z, acc[3]+bias.w);
          *(uint2*)&q_s[swz256i(m, nb)] = o;
        } else if (mat == 1) {
          uint2 o; o.x = pk2(acc[0]+bias.x, acc[1]+bias.y);
                   o.y = pk2(acc[2]+bias.z, acc[3]+bias.w);
          *(uint2*)&k_s[swz256i(m, nb)] = o;
        } else {
          vt_s[(nb+0)*VTS + m] = f2b(acc[0]+bias.x);
          vt_s[(nb+1)*VTS + m] = f2b(acc[1]+bias.y);
          vt_s[(nb+2)*VTS + m] = f2b(acc[2]+bias.z);
          vt_s[(nb+3)*VTS + m] = f2b(acc[3]+bias.w);
        }
      }
    }
  }
  __syncthreads();
  // ---- attention: NO barriers (q/k/vt read-only; P stays in registers) ----

  const float C1 = 0.17677669529663687f * 1.4426950408889634f;  // scale * log2e
  const short8 ones = {16256,16256,16256,16256,16256,16256,16256,16256};  // bf16 1.0
  const short8 z8 = {0,0,0,0,0,0,0,0};
  const float4* cbase = comb4 + ((size_t)(w*NH)*4 + rt)*4*64 + lane;  // + h*1024 per head

  // hoist BOTH heads' Q/K fragments: 10 b128 LDS reads issue back-to-back,
  // latency amortized over both heads' MFMA+exp work (no setprio fences).
  short8 aq2[2], kb2[2][4];
  #pragma unroll
  for (int hh = 0; hh < 2; ++hh) {
    const int h = hp*2 + hh;
    aq2[hh] = *(const short8*)&q_s[swz256i(mbw+ln, h*32 + lg*8)];
    #pragma unroll
    for (int nt = 0; nt < 4; ++nt)
      kb2[hh][nt] = *(const short8*)&k_s[swz256i(krow(nt, ln), h*32 + lg*8)];
  }

  #pragma unroll
  for (int hh = 0; hh < 2; ++hh) {
    const int h = hp*2 + hh;
    // lane-coalesced combined bias+mask: 4 contiguous-1KB loads
    float4 cb[4];
    #pragma unroll
    for (int nt = 0; nt < 4; ++nt)
      cb[nt] = cbase[h*1024 + nt*64];

    // ---- S^T via mfma(K,Q) with permuted K rows ----
    f32x4 st[4];
    #pragma unroll
    for (int nt = 0; nt < 4; ++nt) {
      f32x4 z = {0.f,0.f,0.f,0.f};
      st[nt] = __builtin_amdgcn_mfma_f32_16x16x32_bf16(kb2[hh][nt], aq2[hh], z, 0,0,0);
    }

    // ---- lane-local max-free exp (UNNORMALIZED); garbage/pad kv -> 0 via comb ----
    // lane holds q=ln, kv = 8lg + 4(nt&1) + r + 32(nt>>1)
    float e[4][4];
    #pragma unroll
    for (int nt = 0; nt < 4; ++nt) {
      float cbv[4] = {cb[nt].x, cb[nt].y, cb[nt].z, cb[nt].w};
      #pragma unroll
      for (int r = 0; r < 4; ++r)
        e[nt][r] = __builtin_amdgcn_exp2f(fmaf(st[nt][r], C1, cbv[r]));
    }

    // ---- P A-fragments assembled IN REGISTERS (unnormalized) ----
    uint4v u0, u1;
    u0.x = pk2(e[0][0], e[0][1]);
    u0.y = pk2(e[0][2], e[0][3]);
    u0.z = pk2(e[1][0], e[1][1]);
    u0.w = pk2(e[1][2], e[1][3]);
    u1.x = pk2(e[2][0], e[2][1]);
    u1.y = pk2(e[2][2], e[2][3]);
    u1.z = pk2(e[3][0], e[3][1]);
    u1.w = pk2(e[3][2], e[3][3]);
    short8 ap0 = __builtin_bit_cast(short8, u0);   // kv 8lg..8lg+7
    short8 ap1 = __builtin_bit_cast(short8, u1);   // kv 32+8lg..+7 (pads are 0)

    // ---- rowsum via mfma(P, ones): sacc[r] = sum_kv P[q=4lg+r][kv] ----
    // runs on the MFMA pipe concurrently with PV; inv needed only at store
    f32x4 sacc = {0.f,0.f,0.f,0.f};
    sacc = __builtin_amdgcn_mfma_f32_16x16x32_bf16(ap0, ones, sacc, 0,0,0);
    sacc = __builtin_amdgcn_mfma_f32_16x16x32_bf16(ap1, ones, sacc, 0,0,0);

    // ---- PV: B = V^T rows; normalize at store ----
    #pragma unroll
    for (int nt = 0; nt < 2; ++nt) {
      const int vr = h*32 + nt*16 + ln;             // output col == vt row
      short8 bv0 = *(const short8*)&vt_s[vr*VTS + lg*8];
      short8 bv1 = z8;
      if (lg < 3) bv1 = *(const short8*)&vt_s[vr*VTS + 32 + lg*8];  // lg=3: ap1 covers kv 56..63 = pads (0)
      f32x4 acc = {0.f,0.f,0.f,0.f};
      acc = __builtin_amdgcn_mfma_f32_16x16x32_bf16(ap0, bv0, acc, 0,0,0);
      acc = __builtin_amdgcn_mfma_f32_16x16x32_bf16(ap1, bv1, acc, 0,0,0);
      if (nt == 0) {   // compute inverses once per head, after sacc is final
        // (placed here so rcp overlaps the second PV MFMA pair)
      }
      const int mr = mbw + 4*lg;
      float inv0 = __builtin_amdgcn_rcpf(sacc[0]);
      float inv1 = __builtin_amdgcn_rcpf(sacc[1]);
      float inv2 = __builtin_amdgcn_rcpf(sacc[2]);
      float inv3 = __builtin_amdgcn_rcpf(sacc[3]);
      out[((size_t)b*S49 + mr + 0)*D128 + vr] = acc[0]*inv0;
      out[((size_t)b*S49 + mr + 1)*D128 + vr] = acc[1]*inv1;
      out[((size_t)b*S49 + mr + 2)*D128 + vr] = acc[2]*inv2;
      out[((size_t)b*S49 + mr + 3)*D128 + vr] = acc[3]*inv3;
    }
  }
}

extern "C" void kernel_launch(void* const* d_in, const int* in_sizes, int n_in,
                              void* d_out, int out_size, void* d_ws, size_t ws_size,
                              hipStream_t stream){
  const float* hs  = (const float*)d_in[0];
  const float* msk = (const float*)d_in[1];
  const float* Wq  = (const float*)d_in[2];
  const float* bq  = (const float*)d_in[3];
  const float* Wk  = (const float*)d_in[4];
  const float* bk  = (const float*)d_in[5];
  const float* Wv  = (const float*)d_in[6];
  const float* bv  = (const float*)d_in[7];
  const float* bt  = (const float*)d_in[8];
  unsigned short* wt = (unsigned short*)d_ws;
  float4* comb4 = (float4*)((char*)d_ws + 98304);
  float* out = (float*)d_out;
  const int B  = in_sizes[0] / (S49*D128);
  const int nW = in_sizes[1] / (S49*S49);
  prep_wt<<<dim3((3*128*128 + 255)/256), dim3(256), 0, stream>>>(Wq, Wk, Wv, wt);
  prep_comb<<<dim3((nW*NH*4*4*64 + 255)/256), dim3(256), 0, stream>>>(msk, bt, comb4, nW);
  swin_attn<<<dim3(B), dim3(512), 0, stream>>>(hs, bq, bk, bv, comb4, wt, out, nW);
}